// Round 1
// baseline (443.448 us; speedup 1.0000x reference)
//
#include <hip/hip_runtime.h>
#include <hip/hip_bf16.h>
#include <cstdint>
#include <cstddef>

#define NENT 100000
#define NREL 100
#define DD   128
#define HH   2
#define KK   64
#define BB   8192

typedef __bf16 bf16x8 __attribute__((ext_vector_type(8)));
typedef float  f32x4  __attribute__((ext_vector_type(4)));

__device__ __forceinline__ unsigned short f2bf(float x) {
    union { float f; unsigned u; } v; v.f = x;
    unsigned r = v.u + 0x7fffu + ((v.u >> 16) & 1u);
    return (unsigned short)(r >> 16);
}
__device__ __forceinline__ float bf2f(unsigned short h) {
    union { unsigned u; float f; } v; v.u = ((unsigned)h) << 16;
    return v.f;
}
__device__ __forceinline__ float leakyf(float x) { return x >= 0.f ? x : 0.2f * x; }
__device__ __forceinline__ float sigmoidf(float x) { return 1.f / (1.f + __expf(-x)); }
__device__ __forceinline__ f32x4 mfma16(bf16x8 a, bf16x8 b, f32x4 c) {
    return __builtin_amdgcn_mfma_f32_16x16x32_bf16(a, b, c, 0, 0, 0);
}

// ---------------- prep kernels ----------------

// renorm rows (max_norm=1) + convert to bf16. one wave per row.
__global__ __launch_bounds__(256) void prep_emb(const float* __restrict__ src,
                                                unsigned short* __restrict__ dst,
                                                int rows) {
    const int lane = threadIdx.x & 63;
    const int row  = blockIdx.x * 4 + (threadIdx.x >> 6);
    if (row >= rows) return;
    const float2 v = *(const float2*)(src + (size_t)row * DD + 2 * lane);
    float sq = v.x * v.x + v.y * v.y;
#pragma unroll
    for (int off = 32; off; off >>= 1) sq += __shfl_xor(sq, off);
    const float n = sqrtf(sq);
    const float s = n > 1.f ? 1.f / (n + 1e-7f) : 1.f;
    unsigned int pk = (unsigned)f2bf(v.x * s) | ((unsigned)f2bf(v.y * s) << 16);
    *(unsigned int*)(dst + (size_t)row * DD + 2 * lane) = pk;
}

__global__ __launch_bounds__(256) void prep_w(
    const float* __restrict__ Wa1, const float* __restrict__ Wa2,
    const float* __restrict__ Wx, const float* __restrict__ W1, const float* __restrict__ W2,
    unsigned short* __restrict__ Wa1b, unsigned short* __restrict__ Wa2b,
    unsigned short* __restrict__ Wxb, unsigned short* __restrict__ W1b,
    unsigned short* __restrict__ W2b) {
    int i = blockIdx.x * 256 + threadIdx.x;
    if (i < 32768)        Wa1b[i]          = f2bf(Wa1[i]);
    else if (i < 49152)   Wa2b[i - 32768]  = f2bf(Wa2[i - 32768]);
    else if (i < 81920)   Wxb[i - 49152]   = f2bf(Wx[i - 49152]);
    else if (i < 147456)  W1b[i - 81920]   = f2bf(W1[i - 81920]);
    else if (i < 212992)  W2b[i - 147456]  = f2bf(W2[i - 147456]);
}

// ---------------- branch attention kernel ----------------
// grid = 3*B blocks, 256 threads (4 waves). block handles one (branch, sample).

__global__ __launch_bounds__(256, 2) void branch_attn(
    const int* __restrict__ u1, const int* __restrict__ u2, const int* __restrict__ cidx,
    const int* __restrict__ adj_e, const int* __restrict__ adj_r,
    const float* __restrict__ ent_f32,
    const unsigned short* __restrict__ ent_bf,
    const unsigned short* __restrict__ rel_bf,
    const unsigned short* __restrict__ Wa1b,
    const unsigned short* __restrict__ Wa2b,
    const float* __restrict__ Wa3,
    float* __restrict__ h_ws, float* __restrict__ s_ws) {
    constexpr int XS = 264;  // X lds row stride (bf16), +8 pad -> 4-bank rotation/row
    constexpr int AS = 136;  // A1 lds row stride (bf16)
    __shared__ __align__(16) unsigned short Xl[64 * XS];
    __shared__ __align__(16) unsigned short A1b[64 * AS];
    __shared__ float hl[DD];
    __shared__ int   tIdx[KK], rIdx[KK];
    __shared__ float red2[2];
    __shared__ float part[4][64];
    __shared__ float wts[KK];

    const int t = threadIdx.x;
    const int lane = t & 63, w = t >> 6;
    const int g = lane >> 4, li = lane & 15;
    const int bid = blockIdx.x;
    const int branch = bid >> 13;       // B == 8192
    const int b = bid & (BB - 1);
    const int* ep = (branch == 0) ? u1 : (branch == 1 ? u2 : cidx);
    const int e = ep[b];

    if (t < KK) {
        tIdx[t] = adj_e[(size_t)e * KK + t];
        rIdx[t] = adj_r[(size_t)e * KK + t];
    }
    float hv = 0.f;
    if (t < DD) hv = ent_f32[(size_t)e * DD + t];
    float sq = hv * hv;
#pragma unroll
    for (int off = 32; off; off >>= 1) sq += __shfl_down(sq, off);
    if (t == 0)  red2[0] = sq;
    if (t == 64) red2[1] = sq;
    __syncthreads();
    {
        const float n = sqrtf(red2[0] + red2[1]);
        const float scl = n > 1.f ? 1.f / (n + 1e-7f) : 1.f;
        if (t < DD) {
            const float x = hv * scl;
            hl[t] = x;
            h_ws[(size_t)bid * DD + t] = x;  // renormed h, reused downstream
        }
    }
    __syncthreads();

    // stage X = [h | r_k] in bf16, 16 rows per wave
    {
        const unsigned int hb =
            (unsigned)f2bf(hl[2 * lane]) | ((unsigned)f2bf(hl[2 * lane + 1]) << 16);
#pragma unroll
        for (int j = 0; j < 16; ++j) {
            const int k = w * 16 + j;
            const unsigned int rv =
                *(const unsigned int*)(rel_bf + (size_t)rIdx[k] * DD + 2 * lane);
            *(unsigned int*)(&Xl[k * XS + 2 * lane]) = hb;
            *(unsigned int*)(&Xl[k * XS + DD + 2 * lane]) = rv;
        }
    }
    __syncthreads();

    // GEMM1: A1[64][128] = relu(X[64][256] @ Wa1^T). waves split N (2 ntiles each).
    f32x4 acc[4][2] = {};
#pragma unroll
    for (int ks = 0; ks < 8; ++ks) {
        const int kb = ks * 32 + g * 8;
        const bf16x8 bw0 = *(const bf16x8*)(Wa1b + ((size_t)(w * 2 + 0) * 16 + li) * 256 + kb);
        const bf16x8 bw1 = *(const bf16x8*)(Wa1b + ((size_t)(w * 2 + 1) * 16 + li) * 256 + kb);
#pragma unroll
        for (int mt = 0; mt < 4; ++mt) {
            const bf16x8 a = *(const bf16x8*)(&Xl[(mt * 16 + li) * XS + kb]);
            acc[mt][0] = mfma16(a, bw0, acc[mt][0]);
            acc[mt][1] = mfma16(a, bw1, acc[mt][1]);
        }
    }
#pragma unroll
    for (int mt = 0; mt < 4; ++mt)
#pragma unroll
        for (int ntl = 0; ntl < 2; ++ntl) {
            const int col = (w * 2 + ntl) * 16 + li;
#pragma unroll
            for (int i = 0; i < 4; ++i) {
                const int row = mt * 16 + g * 4 + i;
                A1b[row * AS + col] = f2bf(fmaxf(acc[mt][ntl][i], 0.f));
            }
        }
    __syncthreads();

    // GEMM2: A2[64][128] = A1 @ Wa2^T (relu applied in a3 stage)
    f32x4 acc2[4][2] = {};
#pragma unroll
    for (int ks = 0; ks < 4; ++ks) {
        const int kb = ks * 32 + g * 8;
        const bf16x8 bw0 = *(const bf16x8*)(Wa2b + ((size_t)(w * 2 + 0) * 16 + li) * DD + kb);
        const bf16x8 bw1 = *(const bf16x8*)(Wa2b + ((size_t)(w * 2 + 1) * 16 + li) * DD + kb);
#pragma unroll
        for (int mt = 0; mt < 4; ++mt) {
            const bf16x8 a = *(const bf16x8*)(&A1b[(mt * 16 + li) * AS + kb]);
            acc2[mt][0] = mfma16(a, bw0, acc2[mt][0]);
            acc2[mt][1] = mfma16(a, bw1, acc2[mt][1]);
        }
    }
    // a3[k] = sigmoid(dot(Wa3, relu(A2[k]))) : per-wave partials then cross-wave sum
    {
        const float w3a = Wa3[w * 32 + li];
        const float w3b = Wa3[w * 32 + 16 + li];
#pragma unroll
        for (int mt = 0; mt < 4; ++mt) {
            float p[4];
#pragma unroll
            for (int i = 0; i < 4; ++i)
                p[i] = fmaxf(acc2[mt][0][i], 0.f) * w3a + fmaxf(acc2[mt][1][i], 0.f) * w3b;
#pragma unroll
            for (int off = 1; off < 16; off <<= 1)
#pragma unroll
                for (int i = 0; i < 4; ++i) p[i] += __shfl_xor(p[i], off);
            if (li == 0) {
#pragma unroll
                for (int i = 0; i < 4; ++i) part[w][mt * 16 + g * 4 + i] = p[i];
            }
        }
    }
    __syncthreads();
    if (t < KK) {
        const float sv = part[0][t] + part[1][t] + part[2][t] + part[3][t];
        const float a = sigmoidf(sv);
        float mx = a;
#pragma unroll
        for (int off = 32; off; off >>= 1) mx = fmaxf(mx, __shfl_xor(mx, off));
        const float ex = __expf(a - mx);
        float sm = ex;
#pragma unroll
        for (int off = 32; off; off >>= 1) sm += __shfl_xor(sm, off);
        wts[t] = ex / sm;
    }
    __syncthreads();
    // s[d] = sum_k w[k] * t[k][d]  (tail rows gathered from renormed bf16 table)
    {
        const int d = t & 127, half = t >> 7;
        float accs = 0.f;
        for (int k = half * 32; k < half * 32 + 32; ++k)
            accs += wts[k] * bf2f(ent_bf[(size_t)tIdx[k] * DD + d]);
        ((float*)part)[t] = accs;
    }
    __syncthreads();
    if (t < DD) {
        const float sv = ((float*)part)[t] + ((float*)part)[DD + t];
        s_ws[(size_t)bid * DD + t] = sv;
    }
}

// ---------------- heads + aggregator kernel ----------------
// 64 samples per block; waves split N (4 ntiles each over 256 cols).

__global__ __launch_bounds__(256, 1) void head_agg(
    const float* __restrict__ s_ws, const float* __restrict__ h_ws,
    const unsigned short* __restrict__ Wxb, const float* __restrict__ bx,
    const unsigned short* __restrict__ W1b, const float* __restrict__ b1,
    const unsigned short* __restrict__ W2b, const float* __restrict__ b2,
    float* __restrict__ agg_ws) {
    constexpr int SBS = 136, HS = 132, YS = 264;
    __shared__ __align__(16) unsigned short SB[64 * SBS];
    __shared__ float HL[64 * HS];
    __shared__ __align__(16) unsigned short Y1[64 * YS];
    __shared__ __align__(16) unsigned short Y2[64 * YS];
    __shared__ float bxl[256], b1l[256], b2l[256];

    const int t = threadIdx.x;
    const int lane = t & 63, w = t >> 6;
    const int g = lane >> 4, li = lane & 15;
    const int r = blockIdx.x >> 7;
    const int m0 = (blockIdx.x & 127) * 64;
    const size_t base = (size_t)r * BB + m0;

    for (int idx = t; idx < 64 * DD; idx += 256) {
        const int row = idx >> 7, c = idx & 127;
        SB[row * SBS + c] = f2bf(s_ws[(base + row) * DD + c]);
        HL[row * HS + c] = h_ws[(base + row) * DD + c];
    }
    bxl[t] = bx[t]; b1l[t] = b1[t]; b2l[t] = b2[t];
    __syncthreads();

    // heads: [64][256] = S[64][128] @ WxFlat^T  (WxFlat row n = Wx[n>>7][n&127][:])
    f32x4 ah[4][4] = {};
#pragma unroll
    for (int ks = 0; ks < 4; ++ks) {
        const int kb = ks * 32 + g * 8;
        bf16x8 bb[4];
#pragma unroll
        for (int ntl = 0; ntl < 4; ++ntl)
            bb[ntl] = *(const bf16x8*)(Wxb + ((size_t)(w * 4 + ntl) * 16 + li) * DD + kb);
#pragma unroll
        for (int mt = 0; mt < 4; ++mt) {
            const bf16x8 a = *(const bf16x8*)(&SB[(mt * 16 + li) * SBS + kb]);
#pragma unroll
            for (int ntl = 0; ntl < 4; ++ntl) ah[mt][ntl] = mfma16(a, bb[ntl], ah[mt][ntl]);
        }
    }
    // vec = leaky(heads + bx); y1 = h + vec; y2 = h * vec
#pragma unroll
    for (int mt = 0; mt < 4; ++mt)
#pragma unroll
        for (int ntl = 0; ntl < 4; ++ntl) {
            const int col = (w * 4 + ntl) * 16 + li;
            const int ee = col & 127;
#pragma unroll
            for (int i = 0; i < 4; ++i) {
                const int row = mt * 16 + g * 4 + i;
                const float v = ah[mt][ntl][i] + bxl[col];
                const float vec = leakyf(v);
                const float hvv = HL[row * HS + ee];
                Y1[row * YS + col] = f2bf(hvv + vec);
                Y2[row * YS + col] = f2bf(hvv * vec);
            }
        }
    __syncthreads();

    f32x4 ac1[4][4] = {};
#pragma unroll
    for (int ks = 0; ks < 8; ++ks) {
        const int kb = ks * 32 + g * 8;
        bf16x8 bb[4];
#pragma unroll
        for (int ntl = 0; ntl < 4; ++ntl)
            bb[ntl] = *(const bf16x8*)(W1b + ((size_t)(w * 4 + ntl) * 16 + li) * 256 + kb);
#pragma unroll
        for (int mt = 0; mt < 4; ++mt) {
            const bf16x8 a = *(const bf16x8*)(&Y1[(mt * 16 + li) * YS + kb]);
#pragma unroll
            for (int ntl = 0; ntl < 4; ++ntl) ac1[mt][ntl] = mfma16(a, bb[ntl], ac1[mt][ntl]);
        }
    }
    f32x4 ac2[4][4] = {};
#pragma unroll
    for (int ks = 0; ks < 8; ++ks) {
        const int kb = ks * 32 + g * 8;
        bf16x8 bb[4];
#pragma unroll
        for (int ntl = 0; ntl < 4; ++ntl)
            bb[ntl] = *(const bf16x8*)(W2b + ((size_t)(w * 4 + ntl) * 16 + li) * 256 + kb);
#pragma unroll
        for (int mt = 0; mt < 4; ++mt) {
            const bf16x8 a = *(const bf16x8*)(&Y2[(mt * 16 + li) * YS + kb]);
#pragma unroll
            for (int ntl = 0; ntl < 4; ++ntl) ac2[mt][ntl] = mfma16(a, bb[ntl], ac2[mt][ntl]);
        }
    }
#pragma unroll
    for (int mt = 0; mt < 4; ++mt)
#pragma unroll
        for (int ntl = 0; ntl < 4; ++ntl) {
            const int col = (w * 4 + ntl) * 16 + li;
#pragma unroll
            for (int i = 0; i < 4; ++i) {
                const int row = mt * 16 + g * 4 + i;
                const float x1 = leakyf(ac1[mt][ntl][i] + b1l[col]);
                const float x2 = leakyf(ac2[mt][ntl][i] + b2l[col]);
                agg_ws[(base + row) * 256 + col] = x1 + x2;
            }
        }
}

// ---------------- final combine ----------------

__global__ __launch_bounds__(256) void final_dot(const float* __restrict__ agg_ws,
                                                 const float* __restrict__ h_ws,
                                                 float* __restrict__ out) {
    const int t = threadIdx.x;
    const int lane = t & 63, w = t >> 6;
    const int b = blockIdx.x * 4 + w;
    const float* a1p = agg_ws + (size_t)b * 256;
    const float* a2p = agg_ws + ((size_t)BB + b) * 256;
    const float* acp = agg_ws + ((size_t)2 * BB + b) * 256;
    float acc = 0.f;
#pragma unroll
    for (int j = lane; j < 256; j += 64) acc += fmaxf(a1p[j], a2p[j]) * acp[j];
    const float* h1p = h_ws + (size_t)b * DD;
    const float* h2p = h_ws + ((size_t)BB + b) * DD;
    const float* hcp = h_ws + ((size_t)2 * BB + b) * DD;
#pragma unroll
    for (int j = lane; j < DD; j += 64) acc += fmaxf(h1p[j], h2p[j]) * hcp[j];
#pragma unroll
    for (int off = 32; off; off >>= 1) acc += __shfl_down(acc, off);
    if (lane == 0) out[b] = sigmoidf(acc);
}

// ---------------- launcher ----------------

extern "C" void kernel_launch(void* const* d_in, const int* in_sizes, int n_in,
                              void* d_out, int out_size, void* d_ws, size_t ws_size,
                              hipStream_t stream) {
    (void)in_sizes; (void)n_in; (void)out_size; (void)ws_size;
    const int*   u1   = (const int*)d_in[0];
    const int*   u2   = (const int*)d_in[1];
    const int*   cI   = (const int*)d_in[2];
    const int*   adjE = (const int*)d_in[3];
    const int*   adjR = (const int*)d_in[4];
    const float* entE = (const float*)d_in[5];
    const float* relE = (const float*)d_in[6];
    const float* Wa1  = (const float*)d_in[7];
    const float* Wa2  = (const float*)d_in[8];
    const float* Wa3  = (const float*)d_in[9];
    const float* Wx   = (const float*)d_in[10];
    const float* bx   = (const float*)d_in[11];
    const float* W1   = (const float*)d_in[12];
    const float* b1   = (const float*)d_in[13];
    const float* W2   = (const float*)d_in[14];
    const float* b2   = (const float*)d_in[15];
    float* out = (float*)d_out;

    char* ws = (char*)d_ws;
    unsigned short* entB = (unsigned short*)(ws);             // 25,600,000 B
    unsigned short* relB = (unsigned short*)(ws + 25600000);  //     25,600 B
    unsigned short* Wa1b = (unsigned short*)(ws + 25625600);  //     65,536 B
    unsigned short* Wa2b = (unsigned short*)(ws + 25691136);  //     32,768 B
    unsigned short* Wxb  = (unsigned short*)(ws + 25723904);  //     65,536 B
    unsigned short* W1b  = (unsigned short*)(ws + 25789440);  //    131,072 B
    unsigned short* W2b  = (unsigned short*)(ws + 25920512);  //    131,072 B
    float* h_ws   = (float*)(ws + 26051584);                  // 12,582,912 B
    float* s_ws   = (float*)(ws + 38634496);                  // 12,582,912 B
    float* agg_ws = (float*)(ws + 51217408);                  // 25,165,824 B
    // total 76,383,232 B

    hipLaunchKernelGGL(prep_emb, dim3(NENT / 4), dim3(256), 0, stream, entE, entB, NENT);
    hipLaunchKernelGGL(prep_emb, dim3(NREL / 4), dim3(256), 0, stream, relE, relB, NREL);
    hipLaunchKernelGGL(prep_w, dim3(832), dim3(256), 0, stream, Wa1, Wa2, Wx, W1, W2,
                       Wa1b, Wa2b, Wxb, W1b, W2b);
    hipLaunchKernelGGL(branch_attn, dim3(3 * BB), dim3(256), 0, stream,
                       u1, u2, cI, adjE, adjR, entE, entB, relB, Wa1b, Wa2b, Wa3, h_ws, s_ws);
    hipLaunchKernelGGL(head_agg, dim3(3 * (BB / 64)), dim3(256), 0, stream,
                       s_ws, h_ws, Wxb, bx, W1b, b1, W2b, b2, agg_ws);
    hipLaunchKernelGGL(final_dot, dim3(BB / 4), dim3(256), 0, stream, agg_ws, h_ws, out);
}

// Round 2
// 236.533 us; speedup vs baseline: 1.8748x; 1.8748x over previous
//
#include <hip/hip_runtime.h>
#include <hip/hip_bf16.h>
#include <cstdint>
#include <cstddef>

#define NENT 100000
#define NREL 100
#define DD   128
#define HH_  2
#define KK   64
#define BB   8192

typedef __bf16 bf16x8 __attribute__((ext_vector_type(8)));
typedef float  f32x4  __attribute__((ext_vector_type(4)));

__device__ __forceinline__ unsigned short f2bf(float x) {
    union { float f; unsigned u; } v; v.f = x;
    unsigned r = v.u + 0x7fffu + ((v.u >> 16) & 1u);
    return (unsigned short)(r >> 16);
}
__device__ __forceinline__ float bf2f(unsigned short h) {
    union { unsigned u; float f; } v; v.u = ((unsigned)h) << 16;
    return v.f;
}
__device__ __forceinline__ float leakyf(float x) { return x >= 0.f ? x : 0.2f * x; }
__device__ __forceinline__ float sigmoidf(float x) { return 1.f / (1.f + __expf(-x)); }
__device__ __forceinline__ f32x4 mfma16(bf16x8 a, bf16x8 b, f32x4 c) {
    return __builtin_amdgcn_mfma_f32_16x16x32_bf16(a, b, c, 0, 0, 0);
}

// ---------------- prep kernels ----------------

// renorm entity rows (max_norm=1) + convert to bf16. one wave per row.
__global__ __launch_bounds__(256) void prep_emb(const float* __restrict__ src,
                                                unsigned short* __restrict__ dst,
                                                int rows) {
    const int lane = threadIdx.x & 63;
    const int row  = blockIdx.x * 4 + (threadIdx.x >> 6);
    if (row >= rows) return;
    const float2 v = *(const float2*)(src + (size_t)row * DD + 2 * lane);
    float sq = v.x * v.x + v.y * v.y;
#pragma unroll
    for (int off = 32; off; off >>= 1) sq += __shfl_xor(sq, off);
    const float n = sqrtf(sq);
    const float s = n > 1.f ? 1.f / (n + 1e-7f) : 1.f;
    unsigned int pk = (unsigned)f2bf(v.x * s) | ((unsigned)f2bf(v.y * s) << 16);
    *(unsigned int*)(dst + (size_t)row * DD + 2 * lane) = pk;
}

__global__ __launch_bounds__(256) void prep_w(
    const float* __restrict__ Wa1, const float* __restrict__ Wa2,
    const float* __restrict__ Wx, const float* __restrict__ W1, const float* __restrict__ W2,
    unsigned short* __restrict__ Wa1b, unsigned short* __restrict__ Wa2b,
    unsigned short* __restrict__ Wxb, unsigned short* __restrict__ W1b,
    unsigned short* __restrict__ W2b) {
    int i = blockIdx.x * 256 + threadIdx.x;
    if (i < 32768)        Wa1b[i]          = f2bf(Wa1[i]);
    else if (i < 49152)   Wa2b[i - 32768]  = f2bf(Wa2[i - 32768]);
    else if (i < 81920)   Wxb[i - 49152]   = f2bf(Wx[i - 49152]);
    else if (i < 147456)  W1b[i - 81920]   = f2bf(W1[i - 81920]);
    else if (i < 212992)  W2b[i - 147456]  = f2bf(W2[i - 147456]);
}

// relP[r][d] = sum_j renorm(rel[r])[j] * Wa1[d][128+j]   (f32 math, bf16 out)
__global__ __launch_bounds__(128) void relp_k(const float* __restrict__ relE,
                                              const float* __restrict__ Wa1f,
                                              unsigned short* __restrict__ relP) {
    __shared__ float rl[DD];
    __shared__ float red[2];
    const int r = blockIdx.x, d = threadIdx.x, lane = d & 63, wv = d >> 6;
    const float v = relE[(size_t)r * DD + d];
    float sq = v * v;
#pragma unroll
    for (int off = 32; off; off >>= 1) sq += __shfl_xor(sq, off);
    if (lane == 0) red[wv] = sq;
    __syncthreads();
    const float n = sqrtf(red[0] + red[1]);
    const float scl = n > 1.f ? 1.f / (n + 1e-7f) : 1.f;
    rl[d] = v * scl;
    __syncthreads();
    float acc = 0.f;
#pragma unroll 4
    for (int j = 0; j < DD; ++j) acc += rl[j] * Wa1f[(size_t)d * 256 + DD + j];
    relP[(size_t)r * DD + d] = f2bf(acc);
}

// gather+renorm h rows (f32) for all 3*B samples. one wave per row.
__global__ __launch_bounds__(256) void hprep(
    const int* __restrict__ u1, const int* __restrict__ u2, const int* __restrict__ cI,
    const float* __restrict__ entE, float* __restrict__ h_ws) {
    const int lane = threadIdx.x & 63;
    const int s = blockIdx.x * 4 + (threadIdx.x >> 6);
    const int branch = s >> 13, b = s & (BB - 1);
    const int e = (branch == 0 ? u1 : branch == 1 ? u2 : cI)[b];
    const float2 v = *(const float2*)(entE + (size_t)e * DD + 2 * lane);
    float sq = v.x * v.x + v.y * v.y;
#pragma unroll
    for (int off = 32; off; off >>= 1) sq += __shfl_xor(sq, off);
    const float n = sqrtf(sq);
    const float scl = n > 1.f ? 1.f / (n + 1e-7f) : 1.f;
    float2 o; o.x = v.x * scl; o.y = v.y * scl;
    *(float2*)(h_ws + (size_t)s * DD + 2 * lane) = o;
}

// HH[s][:] = h_s @ Wa1[:, :128]^T   (batched MFMA GEMM, 64 samples/block)
__global__ __launch_bounds__(256) void hh_gemm(
    const int* __restrict__ u1, const int* __restrict__ u2, const int* __restrict__ cI,
    const unsigned short* __restrict__ entB,
    const unsigned short* __restrict__ Wa1b,
    float* __restrict__ HHo) {
    constexpr int AS = 136;
    __shared__ __align__(16) unsigned short AL[64 * AS];
    __shared__ int eL[64];
    const int t = threadIdx.x, lane = t & 63, w = t >> 6, g = lane >> 4, li = lane & 15;
    const int m0 = blockIdx.x * 64;
    const int branch = m0 >> 13, b0 = m0 & (BB - 1);
    const int* ep = branch == 0 ? u1 : branch == 1 ? u2 : cI;
    if (t < 64) eL[t] = ep[b0 + t];
    __syncthreads();
    for (int idx = t; idx < 4096; idx += 256) {
        const int row = idx >> 6, cc = idx & 63;
        *(unsigned int*)&AL[row * AS + cc * 2] =
            ((const unsigned int*)(entB + (size_t)eL[row] * DD))[cc];
    }
    __syncthreads();
    f32x4 acc[4][2] = {};
#pragma unroll
    for (int ks = 0; ks < 4; ++ks) {
        const int kb = ks * 32 + g * 8;
        const bf16x8 bw0 = *(const bf16x8*)(Wa1b + (size_t)((w * 2 + 0) * 16 + li) * 256 + kb);
        const bf16x8 bw1 = *(const bf16x8*)(Wa1b + (size_t)((w * 2 + 1) * 16 + li) * 256 + kb);
#pragma unroll
        for (int mt = 0; mt < 4; ++mt) {
            const bf16x8 a = *(const bf16x8*)(&AL[(mt * 16 + li) * AS + kb]);
            acc[mt][0] = mfma16(a, bw0, acc[mt][0]);
            acc[mt][1] = mfma16(a, bw1, acc[mt][1]);
        }
    }
#pragma unroll
    for (int mt = 0; mt < 4; ++mt)
#pragma unroll
        for (int ntl = 0; ntl < 2; ++ntl) {
            const int col = (w * 2 + ntl) * 16 + li;
#pragma unroll
            for (int i = 0; i < 4; ++i) {
                const int row = mt * 16 + g * 4 + i;
                HHo[(size_t)(m0 + row) * DD + col] = acc[mt][ntl][i];
            }
        }
}

// ---------------- branch attention kernel v2 ----------------
// grid = 3*B/4 blocks, 256 threads (4 waves). one sample per wave.

__global__ __launch_bounds__(256, 3) void branch_attn2(
    const int* __restrict__ u1, const int* __restrict__ u2, const int* __restrict__ cI,
    const int* __restrict__ adj_e, const int* __restrict__ adj_r,
    const unsigned short* __restrict__ entB,
    const unsigned short* __restrict__ relP,
    const unsigned short* __restrict__ Wa2b,
    const float* __restrict__ Wa3,
    const float* __restrict__ HHi,
    unsigned short* __restrict__ s_bf) {
    __shared__ __align__(16) unsigned short PL[NREL * DD];  // swizzled, 25600 B
    __shared__ int   tI[4][KK];
    __shared__ int   rI[4][KK];
    __shared__ float aS[4][KK];
    __shared__ float wS[4][KK];

    const int t = threadIdx.x;
    const int lane = t & 63, w = t >> 6;
    const int g = lane >> 4, li = lane & 15;

    // stage P table swizzled: byte ^= ((row&7)<<4)
    {
        const unsigned int* src = (const unsigned int*)relP;
        unsigned int* dst = (unsigned int*)PL;
#pragma unroll
        for (int it = 0; it < 25; ++it) {
            const int idx = t + it * 256;
            const int row = idx >> 6;
            dst[idx ^ ((row & 7) << 2)] = src[idx];
        }
    }

    const int s = blockIdx.x * 4 + w;
    const int branch = s >> 13, b = s & (BB - 1);
    const int e = (branch == 0 ? u1 : branch == 1 ? u2 : cI)[b];
    tI[w][lane] = adj_e[(size_t)e * KK + lane];
    rI[w][lane] = adj_r[(size_t)e * KK + lane];

    float hh8[4][8];
#pragma unroll
    for (int ks = 0; ks < 4; ++ks) {
        const float* p = HHi + (size_t)s * DD + ks * 32 + g * 8;
        *(f32x4*)&hh8[ks][0] = *(const f32x4*)p;
        *(f32x4*)&hh8[ks][4] = *(const f32x4*)(p + 4);
    }
    float w3v[8];
#pragma unroll
    for (int nt = 0; nt < 8; ++nt) w3v[nt] = Wa3[nt * 16 + li];

    __syncthreads();

    // build A fragments in registers: A1[k] = relu(hh + P[r_k])
    bf16x8 afr[4][4];
#pragma unroll
    for (int mt = 0; mt < 4; ++mt) {
        const int rr = rI[w][mt * 16 + li];
        const int base = (rr << 7) | (g << 3);     // u16 index
        const int sw = (rr & 7) << 3;              // swizzle (u16 units)
#pragma unroll
        for (int ks = 0; ks < 4; ++ks) {
            const bf16x8 pv = *(const bf16x8*)(PL + ((base + (ks << 5)) ^ sw));
#pragma unroll
            for (int j = 0; j < 8; ++j)
                afr[mt][ks][j] = (__bf16)fmaxf((float)pv[j] + hh8[ks][j], 0.f);
        }
    }

    // GEMM2 (A1 @ Wa2^T) fused with a3 = Wa3 . relu(A2)
    float pd[4][4] = {{0.f}};
#pragma unroll 2
    for (int nt = 0; nt < 8; ++nt) {
        bf16x8 bfr[4];
#pragma unroll
        for (int ks = 0; ks < 4; ++ks)
            bfr[ks] = *(const bf16x8*)(Wa2b + (size_t)(nt * 16 + li) * DD + ks * 32 + g * 8);
        f32x4 acc[4] = {};
#pragma unroll
        for (int ks = 0; ks < 4; ++ks)
#pragma unroll
            for (int mt = 0; mt < 4; ++mt) acc[mt] = mfma16(afr[mt][ks], bfr[ks], acc[mt]);
        const float w3 = w3v[nt];
#pragma unroll
        for (int mt = 0; mt < 4; ++mt)
#pragma unroll
            for (int i = 0; i < 4; ++i) pd[mt][i] += fmaxf(acc[mt][i], 0.f) * w3;
    }
    // reduce dot over the 16 li-lanes
#pragma unroll
    for (int off = 1; off < 16; off <<= 1)
#pragma unroll
        for (int mt = 0; mt < 4; ++mt)
#pragma unroll
            for (int i = 0; i < 4; ++i) pd[mt][i] += __shfl_xor(pd[mt][i], off);
    if (li == 0) {
#pragma unroll
        for (int mt = 0; mt < 4; ++mt)
#pragma unroll
            for (int i = 0; i < 4; ++i) aS[w][mt * 16 + g * 4 + i] = pd[mt][i];
    }
    __syncthreads();

    // softmax over sigmoid(a), one wave = one sample
    {
        const float av = sigmoidf(aS[w][lane]);
        float mx = av;
#pragma unroll
        for (int off = 32; off; off >>= 1) mx = fmaxf(mx, __shfl_xor(mx, off));
        const float ex = __expf(av - mx);
        float sm = ex;
#pragma unroll
        for (int off = 32; off; off >>= 1) sm += __shfl_xor(sm, off);
        wS[w][lane] = ex / sm;
    }
    __syncthreads();

    // weighted tail sum: s[d] = sum_k w[k] * T[t_k][d]
    {
        const int gg = lane >> 4, c0 = (lane & 15) * 8;
        float s8[8] = {0.f};
#pragma unroll
        for (int j = 0; j < 16; ++j) {
            const int r = gg * 16 + j;
            const bf16x8 tv = *(const bf16x8*)(entB + (size_t)tI[w][r] * DD + c0);
            const float wt = wS[w][r];
#pragma unroll
            for (int jj = 0; jj < 8; ++jj) s8[jj] += wt * (float)tv[jj];
        }
#pragma unroll
        for (int jj = 0; jj < 8; ++jj) {
            s8[jj] += __shfl_xor(s8[jj], 16);
            s8[jj] += __shfl_xor(s8[jj], 32);
        }
        if (lane < 16) {
            union { bf16x8 v; unsigned short u[8]; } sv;
#pragma unroll
            for (int jj = 0; jj < 8; ++jj) sv.u[jj] = f2bf(s8[jj]);
            *(bf16x8*)(s_bf + (size_t)s * DD + c0) = sv.v;
        }
    }
}

// ---------------- heads + aggregator kernel ----------------

__global__ __launch_bounds__(256, 1) void head_agg(
    const unsigned short* __restrict__ s_bf, const float* __restrict__ h_ws,
    const unsigned short* __restrict__ Wxb, const float* __restrict__ bx,
    const unsigned short* __restrict__ W1b, const float* __restrict__ b1,
    const unsigned short* __restrict__ W2b, const float* __restrict__ b2,
    float* __restrict__ agg_ws) {
    constexpr int SBS = 136, HS = 132, YS = 264;
    __shared__ __align__(16) unsigned short SB[64 * SBS];
    __shared__ float HL[64 * HS];
    __shared__ __align__(16) unsigned short Y1[64 * YS];
    __shared__ __align__(16) unsigned short Y2[64 * YS];
    __shared__ float bxl[256], b1l[256], b2l[256];

    const int t = threadIdx.x;
    const int lane = t & 63, w = t >> 6;
    const int g = lane >> 4, li = lane & 15;
    const int r = blockIdx.x >> 7;
    const int m0 = (blockIdx.x & 127) * 64;
    const size_t base = (size_t)r * BB + m0;

    for (int idx = t; idx < 4096; idx += 256) {
        const int row = idx >> 6, cc = idx & 63;
        *(unsigned int*)&SB[row * SBS + cc * 2] =
            ((const unsigned int*)(s_bf + (base + row) * DD))[cc];
    }
    for (int idx = t; idx < 8192; idx += 256) {
        const int row = idx >> 7, c = idx & 127;
        HL[row * HS + c] = h_ws[(base + row) * DD + c];
    }
    bxl[t] = bx[t]; b1l[t] = b1[t]; b2l[t] = b2[t];
    __syncthreads();

    f32x4 ah[4][4] = {};
#pragma unroll
    for (int ks = 0; ks < 4; ++ks) {
        const int kb = ks * 32 + g * 8;
        bf16x8 bb[4];
#pragma unroll
        for (int ntl = 0; ntl < 4; ++ntl)
            bb[ntl] = *(const bf16x8*)(Wxb + ((size_t)(w * 4 + ntl) * 16 + li) * DD + kb);
#pragma unroll
        for (int mt = 0; mt < 4; ++mt) {
            const bf16x8 a = *(const bf16x8*)(&SB[(mt * 16 + li) * SBS + kb]);
#pragma unroll
            for (int ntl = 0; ntl < 4; ++ntl) ah[mt][ntl] = mfma16(a, bb[ntl], ah[mt][ntl]);
        }
    }
#pragma unroll
    for (int mt = 0; mt < 4; ++mt)
#pragma unroll
        for (int ntl = 0; ntl < 4; ++ntl) {
            const int col = (w * 4 + ntl) * 16 + li;
            const int ee = col & 127;
#pragma unroll
            for (int i = 0; i < 4; ++i) {
                const int row = mt * 16 + g * 4 + i;
                const float v = ah[mt][ntl][i] + bxl[col];
                const float vec = leakyf(v);
                const float hvv = HL[row * HS + ee];
                Y1[row * YS + col] = f2bf(hvv + vec);
                Y2[row * YS + col] = f2bf(hvv * vec);
            }
        }
    __syncthreads();

    f32x4 ac1[4][4] = {};
#pragma unroll
    for (int ks = 0; ks < 8; ++ks) {
        const int kb = ks * 32 + g * 8;
        bf16x8 bb[4];
#pragma unroll
        for (int ntl = 0; ntl < 4; ++ntl)
            bb[ntl] = *(const bf16x8*)(W1b + ((size_t)(w * 4 + ntl) * 16 + li) * 256 + kb);
#pragma unroll
        for (int mt = 0; mt < 4; ++mt) {
            const bf16x8 a = *(const bf16x8*)(&Y1[(mt * 16 + li) * YS + kb]);
#pragma unroll
            for (int ntl = 0; ntl < 4; ++ntl) ac1[mt][ntl] = mfma16(a, bb[ntl], ac1[mt][ntl]);
        }
    }
    f32x4 ac2[4][4] = {};
#pragma unroll
    for (int ks = 0; ks < 8; ++ks) {
        const int kb = ks * 32 + g * 8;
        bf16x8 bb[4];
#pragma unroll
        for (int ntl = 0; ntl < 4; ++ntl)
            bb[ntl] = *(const bf16x8*)(W2b + ((size_t)(w * 4 + ntl) * 16 + li) * 256 + kb);
#pragma unroll
        for (int mt = 0; mt < 4; ++mt) {
            const bf16x8 a = *(const bf16x8*)(&Y2[(mt * 16 + li) * YS + kb]);
#pragma unroll
            for (int ntl = 0; ntl < 4; ++ntl) ac2[mt][ntl] = mfma16(a, bb[ntl], ac2[mt][ntl]);
        }
    }
#pragma unroll
    for (int mt = 0; mt < 4; ++mt)
#pragma unroll
        for (int ntl = 0; ntl < 4; ++ntl) {
            const int col = (w * 4 + ntl) * 16 + li;
#pragma unroll
            for (int i = 0; i < 4; ++i) {
                const int row = mt * 16 + g * 4 + i;
                const float x1 = leakyf(ac1[mt][ntl][i] + b1l[col]);
                const float x2 = leakyf(ac2[mt][ntl][i] + b2l[col]);
                agg_ws[(base + row) * 256 + col] = x1 + x2;
            }
        }
}

// ---------------- final combine ----------------

__global__ __launch_bounds__(256) void final_dot(const float* __restrict__ agg_ws,
                                                 const float* __restrict__ h_ws,
                                                 float* __restrict__ out) {
    const int t = threadIdx.x;
    const int lane = t & 63, w = t >> 6;
    const int b = blockIdx.x * 4 + w;
    const float* a1p = agg_ws + (size_t)b * 256;
    const float* a2p = agg_ws + ((size_t)BB + b) * 256;
    const float* acp = agg_ws + ((size_t)2 * BB + b) * 256;
    float acc = 0.f;
#pragma unroll
    for (int j = lane; j < 256; j += 64) acc += fmaxf(a1p[j], a2p[j]) * acp[j];
    const float* h1p = h_ws + (size_t)b * DD;
    const float* h2p = h_ws + ((size_t)BB + b) * DD;
    const float* hcp = h_ws + ((size_t)2 * BB + b) * DD;
#pragma unroll
    for (int j = lane; j < DD; j += 64) acc += fmaxf(h1p[j], h2p[j]) * hcp[j];
#pragma unroll
    for (int off = 32; off; off >>= 1) acc += __shfl_down(acc, off);
    if (lane == 0) out[b] = sigmoidf(acc);
}

// ---------------- launcher ----------------

extern "C" void kernel_launch(void* const* d_in, const int* in_sizes, int n_in,
                              void* d_out, int out_size, void* d_ws, size_t ws_size,
                              hipStream_t stream) {
    (void)in_sizes; (void)n_in; (void)out_size; (void)ws_size;
    const int*   u1   = (const int*)d_in[0];
    const int*   u2   = (const int*)d_in[1];
    const int*   cI   = (const int*)d_in[2];
    const int*   adjE = (const int*)d_in[3];
    const int*   adjR = (const int*)d_in[4];
    const float* entE = (const float*)d_in[5];
    const float* relE = (const float*)d_in[6];
    const float* Wa1  = (const float*)d_in[7];
    const float* Wa2  = (const float*)d_in[8];
    const float* Wa3  = (const float*)d_in[9];
    const float* Wx   = (const float*)d_in[10];
    const float* bx   = (const float*)d_in[11];
    const float* W1   = (const float*)d_in[12];
    const float* b1   = (const float*)d_in[13];
    const float* W2   = (const float*)d_in[14];
    const float* b2   = (const float*)d_in[15];
    float* out = (float*)d_out;

    char* ws = (char*)d_ws;
    // region 0 is entB during the branch phase, then reused as agg_ws
    unsigned short* entB = (unsigned short*)(ws);              // 25,600,000 B
    float*          agg_ws = (float*)(ws);                     // 25,165,824 B (aliases entB)
    unsigned short* Wa1b = (unsigned short*)(ws + 25600000);   //     65,536 B
    unsigned short* Wa2b = (unsigned short*)(ws + 25665536);   //     32,768 B
    unsigned short* Wxb  = (unsigned short*)(ws + 25698304);   //     65,536 B
    unsigned short* W1b  = (unsigned short*)(ws + 25763840);   //    131,072 B
    unsigned short* W2b  = (unsigned short*)(ws + 25894912);   //    131,072 B
    unsigned short* relP = (unsigned short*)(ws + 26025984);   //     25,600 B
    float* HHp  = (float*)(ws + 26051584);                     // 12,582,912 B
    float* h_ws = (float*)(ws + 38634496);                     // 12,582,912 B
    unsigned short* s_bf = (unsigned short*)(ws + 51217408);   //  6,291,456 B
    // total 57,508,864 B

    hipLaunchKernelGGL(prep_emb, dim3(NENT / 4), dim3(256), 0, stream, entE, entB, NENT);
    hipLaunchKernelGGL(prep_w, dim3(832), dim3(256), 0, stream, Wa1, Wa2, Wx, W1, W2,
                       Wa1b, Wa2b, Wxb, W1b, W2b);
    hipLaunchKernelGGL(relp_k, dim3(NREL), dim3(128), 0, stream, relE, Wa1, relP);
    hipLaunchKernelGGL(hprep, dim3(3 * BB / 4), dim3(256), 0, stream, u1, u2, cI, entE, h_ws);
    hipLaunchKernelGGL(hh_gemm, dim3(3 * BB / 64), dim3(256), 0, stream,
                       u1, u2, cI, entB, Wa1b, HHp);
    hipLaunchKernelGGL(branch_attn2, dim3(3 * BB / 4), dim3(256), 0, stream,
                       u1, u2, cI, adjE, adjR, entB, relP, Wa2b, Wa3, HHp, s_bf);
    hipLaunchKernelGGL(head_agg, dim3(3 * (BB / 64)), dim3(256), 0, stream,
                       s_bf, h_ws, Wxb, bx, W1b, b1, W2b, b2, agg_ws);
    hipLaunchKernelGGL(final_dot, dim3(BB / 4), dim3(256), 0, stream, agg_ws, h_ws, out);
}